// Round 1
// baseline (239.538 us; speedup 1.0000x reference)
//
#include <hip/hip_runtime.h>
#include <hip/hip_bf16.h>
#include <cstdint>

// ---------------------------------------------------------------------------
// MoE CNN, hard top-1 dispatch. Round 20:
//  - conv1 + conv2 FUSED into one per-sample kernel k_conv12 (grid 1024).
//    conv1's verified strip pipeline writes pooled output straight into LDS
//    in conv2's [row18][cig8][col18] uint4 halo layout (no h1 global
//    round-trip: kills 32 MB write + 47 MB logical re-read + conv2's entire
//    global->LDS staging phase + one kernel launch).
//  - conv2 phase widened to acc[2][4] (all 16 rows per wave): each prefetched
//    A weight pair now covers 8 MFMAs instead of 4, halving exposed L2
//    latency per MFMA. 288 MFMA/wave. Reg cost lands at 2 waves/SIMD, which
//    the 64.8 KB LDS already caps at -> free.
// Sizes: B=1024, Cin=3, HW=32, GC=16, E=4, C1=64, C2=128, FC_IN=8192, NC=100
// Output: [final 1024*100][probs 1024*4][aux 1]
// ---------------------------------------------------------------------------

#define B_TOT 1024

typedef __attribute__((ext_vector_type(8))) short short8;
typedef __attribute__((ext_vector_type(16))) float f32x16;

__device__ __forceinline__ ushort f2bf(float f) {
  uint32_t u = __float_as_uint(f);
  u += 0x7fffu + ((u >> 16) & 1u);  // round-to-nearest-even
  return (ushort)(u >> 16);
}

// ------- K0: w2 fp32 [e][cout][ci][3][3] -> bf16 [e][kk][kb 8][cout 128][8] -
__global__ __launch_bounds__(256) void k_wprep(const float* __restrict__ w2,
                                               ushort* __restrict__ wp) {
  const int i = blockIdx.x * 256 + threadIdx.x;  // 294912 total
  const int j = i & 7;
  const int cout = (i >> 3) & 127;
  const int kb = (i >> 10) & 7;
  const int kkE = i >> 13;          // e*9 + kk
  const int kk = kkE - (kkE / 9) * 9;
  const int e = kkE / 9;
  const int ci = kb * 8 + j;
  const float f = w2[(size_t)(((e * 128 + cout) * 64 + ci) * 9) + kk];
  wp[i] = f2bf(f);
}

// ------- K0c: w1 fp32 [e][64][3][3][3] -> bf16 wA [e][kb 4][cout 64][8] ----
__global__ __launch_bounds__(256) void k_w1prep(const float* __restrict__ w1,
                                                ushort* __restrict__ wA) {
  const int i = blockIdx.x * 256 + threadIdx.x;  // 32768 total
  const int j = i & 7;
  const int cout = (i >> 3) & 63;
  const int kb = (i >> 9) & 3;
  const int e = i >> 11;
  const int k = kb * 8 + j;
  float f = 0.f;
  if (k < 27) {
    const int ci = k / 9;
    const int kk = k - ci * 9;
    f = w1[(size_t)(((e * 64 + cout) * 3 + ci) * 9) + kk];
  }
  wA[i] = f2bf(f);
}

// ---------------- K0b: efw fp32 [e][100][8192] -> bf16 [e][kb][cout128][8] -
__global__ __launch_bounds__(256) void k_wfc(const float* __restrict__ efw,
                                             ushort* __restrict__ wfc) {
  const int i = blockIdx.x * 256 + threadIdx.x;  // 4194304 total
  const int j = i & 7;
  const int cout = (i >> 3) & 127;
  const int kb = (i >> 10) & 1023;
  const int e = i >> 20;
  const int k = kb * 8 + j;
  float f = 0.f;
  if (cout < 100) f = efw[((size_t)(e * 100 + cout)) * 8192 + k];
  wfc[i] = f2bf(f);
}

// ---------------- K1: gate conv(3->16)+relu+gap, LDS halo, maskless --------
__global__ __launch_bounds__(256, 2) void k_gate(
    const float* __restrict__ x, const float* __restrict__ gcw,
    const float* __restrict__ gcb, float* __restrict__ g_mean) {
  __shared__ float xs[3 * 34 * 34];  // 13872 B zero-padded halo
  __shared__ float red[4 * 16];
  const int b = blockIdx.x;
  const int t = threadIdx.x;
  const float* xb = x + (size_t)b * 3072;

  for (int c = t; c < 3468; c += 256) {
    const int ci = c / 1156;
    const int rem = c - ci * 1156;
    const int y = rem / 34;
    const int xx = rem - y * 34;
    const int gy = y - 1, gx = xx - 1;
    float v = 0.f;
    if (gy >= 0 && gy < 32 && gx >= 0 && gx < 32) v = xb[ci * 1024 + gy * 32 + gx];
    xs[c] = v;
  }
  __syncthreads();

  const int r = t >> 3;        // output row 0..31
  const int c0 = (t & 7) * 4;  // output col base

  float accp[16][4];
#pragma unroll
  for (int c = 0; c < 16; c++)
#pragma unroll
    for (int p = 0; p < 4; p++) accp[c][p] = 0.f;

#pragma unroll
  for (int ci = 0; ci < 3; ci++) {
    float pv[3][6];
#pragma unroll
    for (int dy = 0; dy < 3; dy++) {
      const float* row = xs + ci * 1156 + (r + dy) * 34 + c0;
#pragma unroll
      for (int dx = 0; dx < 6; dx++) pv[dy][dx] = row[dx];
    }
#pragma unroll
    for (int c = 0; c < 16; c++) {
      const float* wr = gcw + (c * 3 + ci) * 9;
#pragma unroll
      for (int ky = 0; ky < 3; ky++)
#pragma unroll
        for (int kx = 0; kx < 3; kx++) {
          const float wv = wr[ky * 3 + kx];
#pragma unroll
          for (int p = 0; p < 4; p++)
            accp[c][p] += wv * pv[ky][kx + p];
        }
    }
  }

  float sums[16];
#pragma unroll
  for (int c = 0; c < 16; c++) {
    const float bb = gcb[c];
    float s = 0.f;
#pragma unroll
    for (int p = 0; p < 4; p++) s += fmaxf(accp[c][p] + bb, 0.f);
    sums[c] = s;
  }

  const int wave = t >> 6, lane = t & 63;
#pragma unroll
  for (int c = 0; c < 16; c++) {
    float v = sums[c];
    for (int o = 32; o > 0; o >>= 1) v += __shfl_down(v, o);
    if (lane == 0) red[wave * 16 + c] = v;
  }
  __syncthreads();
  if (t < 16) {
    g_mean[b * 16 + t] =
        (red[t] + red[16 + t] + red[32 + t] + red[48 + t]) * (1.f / 1024.f);
  }
}

// ---------------- K2: fused router+softmax+argmax+offsets+scatter+aux ------
// Single block, 256 threads — no cross-block ordering assumptions.
__global__ __launch_bounds__(256) void k_route(
    const float* __restrict__ g_mean, const float* __restrict__ gfw,
    const float* __restrict__ gfb, float* __restrict__ probs,
    float* __restrict__ best_w, int* __restrict__ best_idx,
    int* __restrict__ off_g, int* __restrict__ counts_g,
    int* __restrict__ order, float* __restrict__ aux_out) {
  __shared__ int cnt[4], ofs[5], cl[4];
  __shared__ short bidx[1024];
  __shared__ float red[16];
  const int t = threadIdx.x;
  if (t < 4) { cnt[t] = 0; cl[t] = 0; }
  __syncthreads();

  float asum[4] = {0.f, 0.f, 0.f, 0.f};
  for (int s = t; s < B_TOT; s += 256) {
    float g[16];
#pragma unroll
    for (int c = 0; c < 16; c++) g[c] = g_mean[s * 16 + c];
    float lg[4];
#pragma unroll
    for (int e = 0; e < 4; e++) {
      float sum = gfb[e];
#pragma unroll
      for (int c = 0; c < 16; c++) sum += g[c] * gfw[e * 16 + c];
      lg[e] = sum;
    }
    const float m = fmaxf(fmaxf(lg[0], lg[1]), fmaxf(lg[2], lg[3]));
    float ex[4], ssum = 0.f;
#pragma unroll
    for (int e = 0; e < 4; e++) { ex[e] = expf(lg[e] - m); ssum += ex[e]; }
    const float inv = 1.f / ssum;
    float p[4];
#pragma unroll
    for (int e = 0; e < 4; e++) {
      p[e] = ex[e] * inv;
      probs[s * 4 + e] = p[e];
      asum[e] += p[e];
    }
    int bi = 0; float bp = p[0];
#pragma unroll
    for (int e = 1; e < 4; e++) if (p[e] > bp) { bp = p[e]; bi = e; }
    best_w[s] = bp;
    best_idx[s] = bi;
    bidx[s] = (short)bi;
    atomicAdd(&cnt[bi], 1);
  }
  __syncthreads();

  if (t == 0) {
    int o = 0;
#pragma unroll
    for (int e = 0; e < 4; e++) { ofs[e] = o; o += ((cnt[e] + 31) & ~31); }
    ofs[4] = o;
#pragma unroll
    for (int i = 0; i < 5; i++) off_g[i] = ofs[i];
#pragma unroll
    for (int e = 0; e < 4; e++) counts_g[e] = cnt[e];
  }
  __syncthreads();

  for (int s = t; s < B_TOT; s += 256) {
    const int e2 = bidx[s];
    const int slot = ofs[e2] + atomicAdd(&cl[e2], 1);
    order[slot] = s;
  }

  // aux loss
  const int wave = t >> 6, lane = t & 63;
#pragma unroll
  for (int e = 0; e < 4; e++) {
    float v = asum[e];
    for (int o = 32; o > 0; o >>= 1) v += __shfl_down(v, o);
    if (lane == 0) red[wave * 4 + e] = v;
  }
  __syncthreads();
  if (t == 0) {
    float aux = 0.f;
#pragma unroll
    for (int e = 0; e < 4; e++) {
      const float mp = (red[e] + red[4 + e] + red[8 + e] + red[12 + e]) * (1.f / 1024.f);
      const float d = mp - 0.25f;
      aux += d * d;
    }
    aux_out[0] = aux * 0.25f;
  }
}

// ---------------- K4: fused conv1+pool+conv2+pool, one block per sample ----
// Phase 1 (conv1): 4 strips of 8 pre-pool rows; verified R15 im2col+MFMA;
//   pooled output written to LDS st[row18][cig8][col18] (uint4 = 8ch bf16),
//   borders pre-zeroed (halo).
// Phase 2 (conv2): verified R17/R18 MFMA loop, B from st, acc[2][4] covers
//   all 16 rows/wave; A prefetch rotation 1 tap ahead (8 MFMAs of cover).
__global__ __launch_bounds__(256, 2) void k_conv12(
    const float* __restrict__ x, const ushort* __restrict__ wA,
    const float* __restrict__ b1, const ushort* __restrict__ wp,
    const float* __restrict__ b2, const int* __restrict__ best_idx,
    ushort* __restrict__ h2q) {
  __shared__ ushort xs[3 * 34 * 34];             // 6936 B: bf16 input halo
  __shared__ __align__(16) ushort Bl[256 * 32];  // 16 KB: conv1 B / conv2 pls
  __shared__ uint4 st[18 * 8 * 18];              // 41472 B: conv1 out halo
  const int b = blockIdx.x;
  const int t = threadIdx.x;
  const int e = __builtin_amdgcn_readfirstlane(best_idx[b]);
  const float* xb = x + (size_t)b * 3072;

  // ---- phase 0: zero st (halo borders) + stage x as bf16 with halo ----
  {
    const uint4 z = make_uint4(0u, 0u, 0u, 0u);
    for (int c = t; c < 2592; c += 256) st[c] = z;
  }
  for (int c = t; c < 3468; c += 256) {
    const int ci = c / 1156;
    const int rem = c - ci * 1156;
    const int y = rem / 34;
    const int xx = rem - y * 34;
    const int gy = y - 1, gx = xx - 1;
    float v = 0.f;
    if (gy >= 0 && gy < 32 && gx >= 0 && gx < 32) v = xb[ci * 1024 + gy * 32 + gx];
    xs[c] = f2bf(v);
  }

  const int lane = t & 63;
  const int wv = t >> 6;
  const int g = wv & 1;        // cout tile (conv1: g*32; conv2: g*64)
  const int ln = lane & 31;
  const int half = lane >> 5;  // k-half

  // conv1 A fragments + bias: strip-invariant, hoisted
  const short8 af0 = *(const short8*)(wA + (size_t)(((e * 4 + half) * 64) + g * 32 + ln) * 8);
  const short8 af1 = *(const short8*)(wA + (size_t)(((e * 4 + 2 + half) * 64) + g * 32 + ln) * 8);
  const float* b1e = b1 + (size_t)e * 64;
  float bias1[16];
#pragma unroll
  for (int r = 0; r < 16; r++)
    bias1[r] = b1e[g * 32 + (r & 3) + 8 * (r >> 2) + 4 * half];

  const int nh = wv >> 1;          // conv1 n-tile group
  const int rr = t >> 5, cc = t & 31;  // Bl build coords (strip-local row, col)
  ushort* stw = (ushort*)st;

  // ---- phase 1: conv1, 4 strips ----
  for (int s = 0; s < 4; s++) {
    __syncthreads();  // prev strip's Bl readers done / phase-0 writes visible
    {
      ushort us[32];
#pragma unroll
      for (int k = 0; k < 32; k++) {
        ushort v = 0;
        if (k < 27) {
          const int ci = k / 9;
          const int tap = k - ci * 9;
          const int dy = tap / 3, dx = tap - dy * 3;
          v = xs[ci * 1156 + (8 * s + rr + dy) * 34 + cc + dx];
        }
        us[k] = v;
      }
      uint4 pk[2];
      uint* pu = (uint*)pk;
#pragma unroll
      for (int w = 0; w < 8; w++)
        pu[w] = (uint)us[w * 2] | ((uint)us[w * 2 + 1] << 16);
      *(uint4*)(Bl + t * 32) = pk[0];
      *(uint4*)(Bl + t * 32 + 8) = pk[1];
      uint4 pk2[2];
      uint* pu2 = (uint*)pk2;
#pragma unroll
      for (int w = 0; w < 8; w++)
        pu2[w] = (uint)us[16 + w * 2] | ((uint)us[16 + w * 2 + 1] << 16);
      *(uint4*)(Bl + t * 32 + 16) = pk2[0];
      *(uint4*)(Bl + t * 32 + 24) = pk2[1];
    }
    __syncthreads();

    f32x16 acc1[4];
#pragma unroll
    for (int tt = 0; tt < 4; tt++)
#pragma unroll
      for (int i = 0; i < 16; i++) acc1[tt][i] = 0.f;

#pragma unroll
    for (int tt = 0; tt < 4; tt++) {
      const ushort* bcol = Bl + (size_t)((nh * 4 + tt) * 32 + ln) * 32;
      const short8 b0 = *(const short8*)(bcol + half * 8);
      const short8 b1v = *(const short8*)(bcol + 16 + half * 8);
      acc1[tt] = __builtin_amdgcn_mfma_f32_32x32x16_bf16(af0, b0, acc1[tt], 0, 0, 0);
      acc1[tt] = __builtin_amdgcn_mfma_f32_32x32x16_bf16(af1, b1v, acc1[tt], 0, 0, 0);
    }

    // epilogue: 2x2 maxpool + bias + relu + bf16 -> st (LDS, halo offset +1)
    const int pc = ln >> 1;
#pragma unroll
    for (int j = 0; j < 2; j++) {
      float pw[16];
#pragma unroll
      for (int r = 0; r < 16; r++) {
        float v = fmaxf(acc1[2 * j][r], acc1[2 * j + 1][r]);
        v = fmaxf(v, __shfl_xor(v, 1));
        pw[r] = fmaxf(v + bias1[r], 0.f);
      }
      if ((lane & 1) == 0) {
        const int prow = 4 * s + nh * 2 + j;  // pooled row 0..15
#pragma unroll
        for (int rg = 0; rg < 4; rg++) {
          uint2 pk;
          pk.x = (uint)f2bf(pw[rg * 4 + 0]) | ((uint)f2bf(pw[rg * 4 + 1]) << 16);
          pk.y = (uint)f2bf(pw[rg * 4 + 2]) | ((uint)f2bf(pw[rg * 4 + 3]) << 16);
          ushort* dst = stw +
              ((size_t)((prow + 1) * 8 + (g * 4 + rg)) * 18 + (pc + 1)) * 8 + 4 * half;
          *(uint2*)dst = pk;
        }
      }
    }
  }
  __syncthreads();  // all st writes visible before conv2 reads

  // ---- phase 2: conv2 from LDS, acc[2][4] = all 16 rows per wave ----
  const int h = wv >> 1;       // row half: rows 8h..8h+7
  const int n = lane & 31;
  const int drow = n >> 4;
  const int col15 = n & 15;
  const int cm0 = g * 64;
  const ushort* wpe = wp + (size_t)e * 73728;
  const short* sbs = (const short*)st;
  // A addr: wpe + kk*8192 + ((c4*2+half)*128 + cm0 + {n, 32+n})*8
  const ushort* abase = wpe + (size_t)(half * 128 + cm0 + n) * 8;

  f32x16 acc[2][4];
#pragma unroll
  for (int m = 0; m < 2; m++)
#pragma unroll
    for (int nt = 0; nt < 4; nt++)
#pragma unroll
      for (int i = 0; i < 16; i++) acc[m][nt][i] = 0.f;

  short8 a0[4], a1[4];  // prefetch tap 0
#pragma unroll
  for (int c4 = 0; c4 < 4; c4++) {
    a0[c4] = *(const short8*)(abase + c4 * 2048);
    a1[c4] = *(const short8*)(abase + c4 * 2048 + 256);
  }

#pragma unroll
  for (int kk = 0; kk < 9; kk++) {
    const int ky = kk / 3;
    const int kx = kk - ky * 3;
#pragma unroll
    for (int c4 = 0; c4 < 4; c4++) {
      const int kb = c4 * 2 + half;
#pragma unroll
      for (int nt = 0; nt < 4; nt++) {
        const int rin = 8 * h + 2 * nt + drow + ky;  // st row 0..17
        const int cin = col15 + kx;                  // st col 0..17
        const short8 bf = *(const short8*)(sbs + ((rin * 8 + kb) * 18 + cin) * 8);
        acc[0][nt] = __builtin_amdgcn_mfma_f32_32x32x16_bf16(a0[c4], bf, acc[0][nt], 0, 0, 0);
        acc[1][nt] = __builtin_amdgcn_mfma_f32_32x32x16_bf16(a1[c4], bf, acc[1][nt], 0, 0, 0);
      }
      if (kk < 8) {  // in-place rotate: overwrite just-consumed regs
        a0[c4] = *(const short8*)(abase + (kk + 1) * 8192 + c4 * 2048);
        a1[c4] = *(const short8*)(abase + (kk + 1) * 8192 + c4 * 2048 + 256);
      }
    }
  }

  // epilogue: fused 2x2 maxpool + bias + relu + bf16 -> pls (reuses Bl, 16 KB)
  // pls layout: [cout 128][prl 8][pc 8] == h2q per-sample layout exactly.
  ushort* pls = (ushort*)Bl;
#pragma unroll
  for (int m = 0; m < 2; m++)
#pragma unroll
    for (int nt = 0; nt < 4; nt++) {
#pragma unroll
      for (int r = 0; r < 16; r++) {
        float v = acc[m][nt][r];
        v = fmaxf(v, __shfl_xor(v, 1));
        v = fmaxf(v, __shfl_xor(v, 16));
        if ((lane & 17) == 0) {  // col even, drow==0
          const int rowm = (r & 3) + 8 * (r >> 2) + 4 * half;
          const int cout = cm0 + m * 32 + rowm;
          const int prl = 4 * h + nt;    // pooled row 0..7
          const int pc2 = (n >> 1) & 7;  // pooled col 0..7
          pls[cout * 64 + prl * 8 + pc2] = f2bf(fmaxf(v + b2[e * 128 + cout], 0.f));
        }
      }
    }
  __syncthreads();

  // coalesced copy: 1024 uint4 -> h2q[b] (contiguous, layouts match)
#pragma unroll
  for (int p = 0; p < 4; p++) {
    const int f16 = p * 256 + t;
    *(uint4*)(h2q + (size_t)b * 8192 + f16 * 8) = ((const uint4*)pls)[f16];
  }
}

// ---------------- K5: FC bf16 MFMA, split-K=16, partial stores (no atomics) -
__global__ __launch_bounds__(256) void k_fc(
    const ushort* __restrict__ h2q, const ushort* __restrict__ wfc,
    const int* __restrict__ order, const int* __restrict__ off,
    const int* __restrict__ counts, float* __restrict__ partial) {
  __shared__ ushort bs[32 * 32 * 8];  // 16 KB
  __shared__ int sid[32];
  const int tix = blockIdx.x;
  const int ks = blockIdx.y;  // K-slice of 512
  const int base = tix * 32;
  if (base >= off[4]) return;
  int e = 0;
#pragma unroll
  for (int i = 1; i < 4; i++) if (base >= off[i]) e = i;
  const int vend = off[e] + counts[e];
  const int t = threadIdx.x;
  if (t < 32) {
    const int pos = base + t;
    sid[t] = (pos < vend) ? order[pos] : -1;
  }
  __syncthreads();

  const int lane = t & 63;
  const int wv = t >> 6;
  const int half = lane >> 5;
  const int mn = lane & 31;
  const int cout0 = wv * 32;
  const int ss = t & 31;
  const int kgrp = t >> 5;
  const int srow = sid[ss] >= 0 ? sid[ss] : 0;
  const ushort* arow = h2q + (size_t)srow * 8192;

  f32x16 acc;
#pragma unroll
  for (int i = 0; i < 16; i++) acc[i] = 0.f;

  const ushort* wbase = wfc + ((size_t)e * 1024 + (size_t)ks * 64) * 1024;
  const short* sb = (const short*)bs;

#pragma unroll
  for (int ch = 0; ch < 2; ch++) {
    const int k0g = ks * 512 + ch * 256;
    if (ch) __syncthreads();
#pragma unroll
    for (int p = 0; p < 4; p++) {
      const int kb = p * 8 + kgrp;
      const uint4 v = *(const uint4*)(arow + k0g + kb * 8);
      *(uint4*)(bs + (kb * 32 + ss) * 8) = v;
    }
    __syncthreads();
#pragma unroll
    for (int kk = 0; kk < 16; kk++) {
      const int kbl = kk * 2 + half;
      const short8 af = *(const short8*)(wbase +
          ((size_t)(ch * 32 + kbl) * 128 + cout0 + mn) * 8);
      const short8 bf = *(const short8*)(sb + (kbl * 32 + mn) * 8);
      acc = __builtin_amdgcn_mfma_f32_32x32x16_bf16(af, bf, acc, 0, 0, 0);
    }
  }

  float* pks = partial + (size_t)ks * 147456;  // 128*1152
#pragma unroll
  for (int r = 0; r < 16; r++) {
    const int cout = cout0 + (r & 3) + 8 * (r >> 2) + 4 * half;
    pks[(size_t)cout * 1152 + base + mn] = acc[r];
  }
}

// ---------------- K5b: reduce 16 K-slices, +bias, *best_w, write out ------
__global__ __launch_bounds__(256) void k_red(
    const float* __restrict__ partial, const float* __restrict__ efb,
    const int* __restrict__ order, const int* __restrict__ off,
    const int* __restrict__ counts, const float* __restrict__ best_w,
    float* __restrict__ out) {
  const int slot = blockIdx.x * 256 + threadIdx.x;
  if (slot >= off[4]) return;
  int e = 0;
#pragma unroll
  for (int i = 1; i < 4; i++) if (slot >= off[i]) e = i;
  if (slot - off[e] >= counts[e]) return;
  const int s = order[slot];
  const float bw = best_w[s];
  const int o0 = blockIdx.y * 4;
#pragma unroll
  for (int j = 0; j < 4; j++) {
    const int o = o0 + j;
    float sum = 0.f;
#pragma unroll
    for (int ks = 0; ks < 16; ks++)
      sum += partial[(size_t)ks * 147456 + (size_t)o * 1152 + slot];
    out[(size_t)s * 100 + o] = (sum + efb[e * 100 + o]) * bw;
  }
}

// ---------------------------------------------------------------------------
extern "C" void kernel_launch(void* const* d_in, const int* in_sizes, int n_in,
                              void* d_out, int out_size, void* d_ws, size_t ws_size,
                              hipStream_t stream) {
  const float* x   = (const float*)d_in[0];
  const float* gcw = (const float*)d_in[1];
  const float* gcb = (const float*)d_in[2];
  const float* gfw = (const float*)d_in[3];
  const float* gfb = (const float*)d_in[4];
  const float* c1w = (const float*)d_in[5];
  const float* c1b = (const float*)d_in[6];
  const float* c2w = (const float*)d_in[7];
  const float* c2b = (const float*)d_in[8];
  const float* efw = (const float*)d_in[9];
  const float* efb = (const float*)d_in[10];
  float* out = (float*)d_out;
  float* ws  = (float*)d_ws;

  // ws layout (float-element offsets)
  float*  g_mean   = ws;                        // 16384
  float*  best_w   = ws + 16384;                // 1024
  int*    best_idx = (int*)(ws + 17408);        // 1024
  int*    counts   = (int*)(ws + 18432);        // 4
  int*    off      = (int*)(ws + 18440);        // 5
  int*    order    = (int*)(ws + 18448);        // 1152
  ushort* wp       = (ushort*)(ws + 20480);     // 294912 us  = 147456 f
  ushort* wfc      = (ushort*)(ws + 167936);    // 4194304 us = 2097152 f
  ushort* h2q      = (ushort*)(ws + 10653696);  // 8388608 us = 4194304 f
  float*  partial  = ws + 14848000;             // 2359296 f
  ushort* wA       = (ushort*)(ws + 17207296);  // 32768 us = 16384 f

  float* probs = out + 102400;
  float* aux   = out + 106496;

  k_wprep<<<1152, 256, 0, stream>>>(c2w, wp);
  k_w1prep<<<128, 256, 0, stream>>>(c1w, wA);
  k_wfc<<<16384, 256, 0, stream>>>(efw, wfc);
  k_gate<<<1024, 256, 0, stream>>>(x, gcw, gcb, g_mean);
  k_route<<<1, 256, 0, stream>>>(g_mean, gfw, gfb, probs, best_w, best_idx,
                                 off, counts, order, aux);
  k_conv12<<<1024, 256, 0, stream>>>(x, wA, c1b, wp, c2b, best_idx, h2q);
  dim3 g5(36, 16);
  k_fc<<<g5, 256, 0, stream>>>(h2q, wfc, order, off, counts, partial);
  dim3 g6(5, 25);
  k_red<<<g6, 256, 0, stream>>>(partial, efb, order, off, counts, best_w, out);
}